// Round 3
// baseline (462.554 us; speedup 1.0000x reference)
//
#include <hip/hip_runtime.h>
#include <math.h>

// Problem constants
constexpr int BB = 2048;     // batch
constexpr int CC = 129;      // channels
constexpr int TT = 200;      // time
constexpr int NPAIR = BB * CC;          // 264192
constexpr int NPG   = NPAIR / 16;       // 16512 pair-groups (16 pairs each)
constexpr int NTILE = NPG * 3;          // 49536 seg-tiles (one 16x16 MFMA tile each)
constexpr int NBLK  = NTILE / 4;        // 12384 blocks (4 waves = 4 tiles per block)

// d_ws layout (in floats)
constexpr int OFF_AVG0 = 8192;          // B-frags occupy 16384 bf16 = 8192 floats
constexpr int OFF_AVG2 = OFF_AVG0 + NPAIR;
constexpr int OFF_MX0  = OFF_AVG2 + NPAIR;
constexpr int OFF_MX2  = OFF_MX0 + NPAIR;
constexpr int OFF_F3   = OFF_MX2 + NPAIR;   // 3 * NPAIR * 4 floats (per-seg partials)

typedef __bf16 bf16x8 __attribute__((ext_vector_type(8)));
typedef float  f32x4  __attribute__((ext_vector_type(4)));

union BFU { int4 v; bf16x8 b; };
union BSU { __bf16 b; unsigned short u; };

// ---------------------------------------------------------------------------
// kInit: build W (128 k-rows x 64 n-cols) as MFMA B-fragments, split bf16
// hi/lo, pre-swizzled in fragment order:
//   bfr[((ks*4+nt)*2+h)*512 + lane*8 + i]  (ushort)
// Element (ks,nt,h,lane,i) = W[k = ks*32 + (lane>>4)*8 + i][n = nt*16 + (lane&15)]
//   n<60: bin kb=(n>>1)+1, even n -> w[t]*cos, odd n -> w[t]*sin
//   n==60: 1/100 (k<100)  -> GEMM emits segment mean (detrend + avg for free)
//   k>=100 or n>60: 0 (K padding / unused cols)
// ---------------------------------------------------------------------------
__global__ void kInit(unsigned short* __restrict__ bfr) {
    int tid = blockIdx.x * 256 + threadIdx.x;
    if (tid >= 16384) return;
    int i    = tid & 7;
    int lane = (tid >> 3) & 63;
    int h    = (tid >> 9) & 1;
    int nt   = (tid >> 10) & 3;
    int ks   = tid >> 12;
    int k = ks * 32 + (lane >> 4) * 8 + i;
    int n = nt * 16 + (lane & 15);
    float v = 0.f;
    if (k < 100) {
        if (n < 60) {
            int kb = (n >> 1) + 1;
            const float C = 0.06283185307179587f;      // 2*pi/100
            float w = 0.5f - 0.5f * cosf(C * (float)k);
            int ph = (kb * k) % 100;                   // exact phase reduction
            float ang = C * (float)ph;
            v = w * ((n & 1) ? sinf(ang) : cosf(ang));
        } else if (n == 60) {
            v = 0.01f;
        }
    }
    __bf16 hb = (__bf16)v;
    BSU out;
    if (h == 0) out.b = hb;
    else        out.b = (__bf16)(v - (float)hb);
    bfr[tid] = out.u;
}

// ---------------------------------------------------------------------------
// Kernel A v4: register-staged, LDS-free, seg-split Welch MFMA.
//
// One wave = one 16x16 M-tile = (16 pairs, 1 segment). tile = blk*4 + wave;
// pg = tile/3, seg = tile%3. All segments share the SAME B table (k is
// within-segment time), so no new tables.
//  - Each lane needs exactly 28 floats of ONE row (k = quad*8+i + 32ks):
//    14 independent float2 loads issued in ONE upfront burst (single
//    vmcnt-covered wait) -- fixes v3's 12 serialized load batches.
//  - split-bf16 cvt once; 48 MFMAs; in-register band reduce (v3's shfl
//    scheme, single tile). Row max falls out of the same registers
//    (seg0: t 0..99, seg2: t 100..199; 2 shfl_xor). seg1 skips max.
//  - Per-seg partials (feat3/avg0/avg2/mx0/mx2) to global; kB combines.
//  - ZERO LDS, ZERO barriers. Bijective XCD swizzle (NBLK%8==0) keeps a
//    pair-group's 3 seg-tiles on one XCD's L2.
// spec = Ah*Bh + Ah*Bl + Al*Bh  (~2^-18 relative error, unchanged).
// ---------------------------------------------------------------------------
__global__ __launch_bounds__(256, 4) void kA(const float* __restrict__ x,
                                             const unsigned short* __restrict__ bfr,
                                             float* __restrict__ avg0,
                                             float* __restrict__ avg2,
                                             float* __restrict__ mx0,
                                             float* __restrict__ mx2,
                                             float* __restrict__ feat3) {
    const int tid  = threadIdx.x;
    // bijective XCD swizzle: NBLK = 12384 = 8 * 1548
    const int blk  = (blockIdx.x & 7) * (NBLK / 8) + (blockIdx.x >> 3);
    const int wv   = tid >> 6;
    const int lane = tid & 63;
    const int tile = blk * 4 + wv;
    const int pg   = tile / 3;
    const int sg   = tile - pg * 3;
    const int quad = lane >> 4, mrow = lane & 15;

    const float* rp = x + (size_t)(pg * 16 + mrow) * TT + sg * 50;

    // ---- A load burst: 14 independent float2 (ks0..2: 12, ks3: 2) ----
    float2 ar[14];
    #pragma unroll
    for (int c = 0; c < 12; c++) {
        int ks = c >> 2, j = c & 3;
        ar[c] = *(const float2*)(rp + ks * 32 + quad * 8 + j * 2);
    }
    ar[12] = *(const float2*)(rp + 96);    // floats 96..99: real for ALL lanes
    ar[13] = *(const float2*)(rp + 98);

    // ---- split-bf16 conversion (once per element) ----
    bf16x8 Ah[4], Al[4];
    #pragma unroll
    for (int ks = 0; ks < 4; ks++) {
        float f[8];
        if (ks < 3) {
            f[0] = ar[ks * 4 + 0].x; f[1] = ar[ks * 4 + 0].y;
            f[2] = ar[ks * 4 + 1].x; f[3] = ar[ks * 4 + 1].y;
            f[4] = ar[ks * 4 + 2].x; f[5] = ar[ks * 4 + 2].y;
            f[6] = ar[ks * 4 + 3].x; f[7] = ar[ks * 4 + 3].y;
        } else {
            // k = 96..127: only k=96..99 real, held by quad==0 slots
            bool v0 = (quad == 0);
            f[0] = v0 ? ar[12].x : 0.f; f[1] = v0 ? ar[12].y : 0.f;
            f[2] = v0 ? ar[13].x : 0.f; f[3] = v0 ? ar[13].y : 0.f;
            f[4] = 0.f; f[5] = 0.f; f[6] = 0.f; f[7] = 0.f;
        }
        #pragma unroll
        for (int i = 0; i < 8; i++) {
            __bf16 hb = (__bf16)f[i];
            Ah[ks][i] = hb;
            Al[ks][i] = (__bf16)(f[i] - (float)hb);
        }
    }

    // ---- row max from the raw registers (seg0: t 0..99, seg2: t 100..199) ----
    if (sg != 1) {
        float m = -3.4e38f;
        #pragma unroll
        for (int c = 0; c < 14; c++) m = fmaxf(m, fmaxf(ar[c].x, ar[c].y));
        m = fmaxf(m, __shfl_xor(m, 16, 64));     // reduce across quads (same mrow)
        m = fmaxf(m, __shfl_xor(m, 32, 64));
        if (quad == 0) (sg == 0 ? mx0 : mx2)[pg * 16 + mrow] = m;
    }

    // ---- MFMA: 1 tile, ks-outer (8 B-frags live at a time) ----
    f32x4 acc[4];
    #pragma unroll
    for (int b = 0; b < 4; b++) acc[b] = f32x4{0.f, 0.f, 0.f, 0.f};

    const int4* bg = (const int4*)bfr;
    #pragma unroll
    for (int ks = 0; ks < 4; ks++) {
        bf16x8 Bh[4], Bl[4];
        #pragma unroll
        for (int nt = 0; nt < 4; nt++) {
            BFU uh, ul;
            uh.v = bg[((ks * 4 + nt) * 2 + 0) * 64 + lane];
            ul.v = bg[((ks * 4 + nt) * 2 + 1) * 64 + lane];
            Bh[nt] = uh.b;
            Bl[nt] = ul.b;
        }
        __builtin_amdgcn_s_setprio(1);
        #pragma unroll
        for (int nt = 0; nt < 4; nt++) {
            acc[nt] = __builtin_amdgcn_mfma_f32_16x16x32_bf16(Al[ks], Bh[nt], acc[nt], 0, 0, 0);
            acc[nt] = __builtin_amdgcn_mfma_f32_16x16x32_bf16(Ah[ks], Bl[nt], acc[nt], 0, 0, 0);
            acc[nt] = __builtin_amdgcn_mfma_f32_16x16x32_bf16(Ah[ks], Bh[nt], acc[nt], 0, 0, 0);
        }
        __builtin_amdgcn_s_setprio(0);
    }

    // ---- in-register per-row band reduce (per-seg partials) ----
    // C/D: acc[nt][i] = spec[row = quad*4 + i][col = nt*16 + mrow]
    // bands (cols): d:0..7  t:6..15  a:14..25  b:24..59; col 0 detrended by 25*mu
    // mu = spec[row][60] at (nt=3, mrow=12).
    float* fout = feat3 + (size_t)sg * NPAIR * 4;
    #pragma unroll
    for (int i = 0; i < 4; i++) {
        float mu = __shfl(acc[3][i], (lane & 48) | 12, 64);
        float v0 = acc[0][i];
        if (mrow == 0) v0 += 25.f * mu;          // detrend re(k=1)
        float w0 = v0 * v0;
        float w1 = acc[1][i] * acc[1][i];
        float w2 = acc[2][i] * acc[2][i];
        float w3 = acc[3][i] * acc[3][i];
        float s0 = (mrow <= 7) ? w0 : 0.f;
        float s1 = (mrow >= 6) ? w0 : 0.f;
        float s2 = ((mrow >= 14) ? w0 : 0.f) + ((mrow <= 9) ? w1 : 0.f);
        float s3 = ((mrow >= 8) ? w1 : 0.f) + w2 + ((mrow <= 11) ? w3 : 0.f);
        #pragma unroll
        for (int m = 1; m <= 8; m <<= 1) {
            s0 += __shfl_xor(s0, m, 16);
            s1 += __shfl_xor(s1, m, 16);
            s2 += __shfl_xor(s2, m, 16);
            s3 += __shfl_xor(s3, m, 16);
        }
        if (mrow == 0) {
            int pr = pg * 16 + quad * 4 + i;
            float4 fo;
            fo.x = s0 * (2.f / 45000.f);
            fo.y = s1 * (2.f / 56250.f);
            fo.z = s2 * (2.f / 67500.f);
            fo.w = s3 * (2.f / 202500.f);
            *(float4*)(fout + (size_t)pr * 4) = fo;
            if (sg == 0) avg0[pr] = mu;
            if (sg == 2) avg2[pr] = mu;
        }
    }
}

// ---------------------------------------------------------------------------
// Kernel B: attention + MLP head. Only change vs v2: combine kA's per-seg
// partials (feat = sum of 3, avg = (mu0+mu2)/2, max = max of two halves).
// ---------------------------------------------------------------------------
__global__ __launch_bounds__(256, 8) void kB(const float* __restrict__ avg0,
                                             const float* __restrict__ avg2,
                                             const float* __restrict__ mx0,
                                             const float* __restrict__ mx2,
                                             const float* __restrict__ feat3,
                                             const float* __restrict__ w_att1,
                                             const float* __restrict__ w_att2,
                                             const float* __restrict__ w_bb,
                                             const float* __restrict__ b_bb,
                                             const float* __restrict__ w_fe1,
                                             const float* __restrict__ b_fe1,
                                             const float* __restrict__ w_fe2,
                                             const float* __restrict__ b_fe2,
                                             const float* __restrict__ w_h1,
                                             const float* __restrict__ b_h1,
                                             const float* __restrict__ w_h2,
                                             const float* __restrict__ b_h2,
                                             const float* __restrict__ w_h3,
                                             const float* __restrict__ b_h3,
                                             float* __restrict__ out) {
    __shared__ float s_avg[132], s_mx[132], s_fq[520];
    __shared__ float s_t1a[16], s_t1b[16], s_t1[16];
    __shared__ float s_v[132];
    __shared__ float s_tf[2][64];
    __shared__ float s_p1[2][128];
    __shared__ float s_f1[128];
    __shared__ float s_p2[4][64];
    __shared__ float s_h[128];
    __shared__ float s_pg1[2][128];
    __shared__ float s_g1[128];
    __shared__ float s_pg2[4][64];

    const int b = blockIdx.x;
    const int tid = threadIdx.x;

    for (int i = tid; i < 129; i += 256) {
        s_avg[i] = (avg0[b * 129 + i] + avg2[b * 129 + i]) * 0.5f;
        s_mx[i]  = fmaxf(mx0[b * 129 + i], mx2[b * 129 + i]);
    }
    {
        const float* f0 = feat3 + (size_t)b * 516;
        const float* f1 = f0 + (size_t)NPAIR * 4;
        const float* f2 = f1 + (size_t)NPAIR * 4;
        for (int i = tid; i < 516; i += 256) s_fq[i] = f0[i] + f1[i] + f2[i];
    }
    __syncthreads();

    if (tid < 32) {
        int h = tid & 15;
        const float* src = (tid >= 16) ? s_mx : s_avg;
        float acc = 0.f;
        #pragma unroll 4
        for (int c = 0; c < 129; c++) acc += src[c] * w_att1[c * 16 + h];
        ((tid >= 16) ? s_t1b : s_t1a)[h] = fmaxf(acc, 0.f);
    }
    __syncthreads();
    if (tid < 16) s_t1[tid] = s_t1a[tid] + s_t1b[tid];
    __syncthreads();

    if (tid < 129) {
        float l = 0.f;
        #pragma unroll
        for (int j = 0; j < 16; j++) l += s_t1[j] * w_att2[j * 129 + tid];
        s_v[tid] = s_avg[tid] / (1.f + expf(-l));
    }
    __syncthreads();

    if (tid < 128) {
        int o = tid & 63, ks = tid >> 6;
        int i0 = ks ? 65 : 0, i1 = ks ? 129 : 65;
        float acc = 0.f;
        #pragma unroll 4
        for (int i = i0; i < i1; i++) acc += s_v[i] * w_bb[i * 64 + o];
        s_tf[ks][o] = acc;
    }
    {
        int o = tid & 127, ks = tid >> 7;
        float acc = 0.f;
        #pragma unroll 4
        for (int i = ks * 258; i < ks * 258 + 258; i++) acc += s_fq[i] * w_fe1[i * 128 + o];
        s_p1[ks][o] = acc;
    }
    __syncthreads();
    if (tid < 64) s_h[tid] = fmaxf(s_tf[0][tid] + s_tf[1][tid] + b_bb[tid], 0.f);
    if (tid >= 128) { int o = tid - 128; s_f1[o] = fmaxf(s_p1[0][o] + s_p1[1][o] + b_fe1[o], 0.f); }
    __syncthreads();

    {
        int o = tid & 63, ks = tid >> 6;
        float acc = 0.f;
        #pragma unroll 4
        for (int i = ks * 32; i < ks * 32 + 32; i++) acc += s_f1[i] * w_fe2[i * 64 + o];
        s_p2[ks][o] = acc;
    }
    __syncthreads();
    if (tid < 64) s_h[64 + tid] = fmaxf(s_p2[0][tid] + s_p2[1][tid] + s_p2[2][tid] + s_p2[3][tid] + b_fe2[tid], 0.f);
    __syncthreads();

    {
        int o = tid & 127, ks = tid >> 7;
        float acc = 0.f;
        #pragma unroll 4
        for (int i = ks * 64; i < ks * 64 + 64; i++) acc += s_h[i] * w_h1[i * 128 + o];
        s_pg1[ks][o] = acc;
    }
    __syncthreads();
    if (tid < 128) s_g1[tid] = fmaxf(s_pg1[0][tid] + s_pg1[1][tid] + b_h1[tid], 0.f);
    __syncthreads();

    {
        int o = tid & 63, ks = tid >> 6;
        float acc = 0.f;
        #pragma unroll 4
        for (int i = ks * 32; i < ks * 32 + 32; i++) acc += s_g1[i] * w_h2[i * 64 + o];
        s_pg2[ks][o] = acc;
    }
    __syncthreads();

    if (tid < 64) {
        float g2 = fmaxf(s_pg2[0][tid] + s_pg2[1][tid] + s_pg2[2][tid] + s_pg2[3][tid] + b_h2[tid], 0.f);
        float pz = g2 * w_h3[tid];
        for (int off = 32; off >= 1; off >>= 1) pz += __shfl_xor(pz, off, 64);
        if (tid == 0) out[b] = pz + b_h3[0];
    }
}

// ---------------------------------------------------------------------------
extern "C" void kernel_launch(void* const* d_in, const int* in_sizes, int n_in,
                              void* d_out, int out_size, void* d_ws, size_t ws_size,
                              hipStream_t stream) {
    const float* x      = (const float*)d_in[0];
    const float* w_att1 = (const float*)d_in[1];
    const float* w_att2 = (const float*)d_in[2];
    const float* w_bb   = (const float*)d_in[3];
    const float* b_bb   = (const float*)d_in[4];
    const float* w_fe1  = (const float*)d_in[5];
    const float* b_fe1  = (const float*)d_in[6];
    const float* w_fe2  = (const float*)d_in[7];
    const float* b_fe2  = (const float*)d_in[8];
    const float* w_h1   = (const float*)d_in[9];
    const float* b_h1   = (const float*)d_in[10];
    const float* w_h2   = (const float*)d_in[11];
    const float* b_h2   = (const float*)d_in[12];
    const float* w_h3   = (const float*)d_in[13];
    const float* b_h3   = (const float*)d_in[14];

    float* ws = (float*)d_ws;
    unsigned short* bfr = (unsigned short*)ws;     // 16384 bf16 = 8192 floats
    float* avg0  = ws + OFF_AVG0;
    float* avg2  = ws + OFF_AVG2;
    float* mx0   = ws + OFF_MX0;
    float* mx2   = ws + OFF_MX2;
    float* feat3 = ws + OFF_F3;

    kInit<<<64, 256, 0, stream>>>(bfr);
    kA<<<NBLK, 256, 0, stream>>>(x, bfr, avg0, avg2, mx0, mx2, feat3);
    kB<<<BB, 256, 0, stream>>>(avg0, avg2, mx0, mx2, feat3,
                               w_att1, w_att2, w_bb, b_bb,
                               w_fe1, b_fe1, w_fe2, b_fe2,
                               w_h1, b_h1, w_h2, b_h2, w_h3, b_h3,
                               (float*)d_out);
}

// Round 4
// 419.130 us; speedup vs baseline: 1.1036x; 1.1036x over previous
//
#include <hip/hip_runtime.h>
#include <math.h>

// Problem constants
constexpr int BB = 2048;     // batch
constexpr int CC = 129;      // channels
constexpr int TT = 200;      // time
constexpr int NPAIR = BB * CC;          // 264192
constexpr int NPG   = NPAIR / 16;       // 16512 pair-groups (16 pairs each)
constexpr int NBLK  = NPG / 4;          // 4128 blocks (4 waves, 1 pg per wave)
constexpr int XSTR  = 204;              // LDS row stride (floats)
constexpr int WSLICE = 16 * XSTR;       // per-wave LDS slice = 3264 floats

// d_ws layout (in floats)
constexpr int OFF_AVG = 8192;           // B-frags occupy 16384 bf16 = 8192 floats
constexpr int OFF_MX  = OFF_AVG + NPAIR;
constexpr int OFF_FT  = OFF_MX + NPAIR; // NPAIR*4 floats

typedef __bf16 bf16x8 __attribute__((ext_vector_type(8)));
typedef float  f32x4  __attribute__((ext_vector_type(4)));

union BFU { int4 v; bf16x8 b; };
union BSU { __bf16 b; unsigned short u; };

// ---------------------------------------------------------------------------
// kInit: build W (128 k-rows x 64 n-cols) as MFMA fragments, split bf16
// hi/lo, pre-swizzled in fragment order:
//   bfr[((ks*4+nt)*2+h)*512 + lane*8 + i]  (ushort)
// Element (ks,nt,h,lane,i) = W[k = ks*32 + (lane>>4)*8 + i][n = nt*16 + (lane&15)]
// NOTE: MFMA A and B fragment layouts are symmetric (16-dim = lane&15,
// K = quad*8+i), so this same buffer serves as the A-operand of W^T in the
// transposed GEMM (v5). No change needed.
//   n<60: bin kb=(n>>1)+1, even n -> w[t]*cos, odd n -> w[t]*sin
//   n==60: 1/100 (k<100)  -> GEMM emits segment mean (detrend + avg for free)
//   k>=100 or n>60: 0 (K padding / unused cols)
// ---------------------------------------------------------------------------
__global__ void kInit(unsigned short* __restrict__ bfr) {
    int tid = blockIdx.x * 256 + threadIdx.x;
    if (tid >= 16384) return;
    int i    = tid & 7;
    int lane = (tid >> 3) & 63;
    int h    = (tid >> 9) & 1;
    int nt   = (tid >> 10) & 3;
    int ks   = tid >> 12;
    int k = ks * 32 + (lane >> 4) * 8 + i;
    int n = nt * 16 + (lane & 15);
    float v = 0.f;
    if (k < 100) {
        if (n < 60) {
            int kb = (n >> 1) + 1;
            const float C = 0.06283185307179587f;      // 2*pi/100
            float w = 0.5f - 0.5f * cosf(C * (float)k);
            int ph = (kb * k) % 100;                   // exact phase reduction
            float ang = C * (float)ph;
            v = w * ((n & 1) ? sinf(ang) : cosf(ang));
        } else if (n == 60) {
            v = 0.01f;
        }
    }
    __bf16 hb = (__bf16)v;
    BSU out;
    if (h == 0) out.b = hb;
    else        out.b = (__bf16)(v - (float)hb);
    bfr[tid] = out.u;
}

// ---------------------------------------------------------------------------
// Kernel A v5: v2 skeleton (LDS-staged, wave-autonomous, zero barriers) +
// TRANSPOSED GEMM for an in-register band reduce.
//
// Wave w owns pair-group pg = blk*4+w (16 pairs). It stages its 16 rows
// (float4-coalesced -> LDS), then computes D = W^T (A operand, the kInit
// table unchanged) x X (B operand, frags read from LDS). Output layout:
//   lane (quad,mrow) holds D[freq j = nt*16+quad*4+i][pair = mrow]
// i.e. 16 freqs of ONE pair per lane -> band reduce is per-lane masked
// v^2 sums + ONE shfl for mu + 2 shfl_xor per band (vs v2's spec-LDS
// round-trip + 60-col serial loops, ~6-7K cycle chain).
//  - all 3 segs in one wave: final feat/avg/max written directly (no
//    partial buffers; kB reverts to simple form).
//  - row max folded into fragment reads (quads of a row jointly cover
//    all 200 samples; 2 shfl_xor).
//  - ks-outer: 8 table frags live (32 VGPR), 16 KB table per 3 tiles.
//  - zero barriers; 3 blocks/CU (LDS 52224 B).
// spec = Wh*Xh + Wl*Xh + Wh*Xl  (same 3 products as before, ~2^-18 rel err).
// ---------------------------------------------------------------------------
__global__ __launch_bounds__(256, 3) void kA(const float* __restrict__ x,
                                             const unsigned short* __restrict__ bfr,
                                             float* __restrict__ avg,
                                             float* __restrict__ mxg,
                                             float* __restrict__ feat) {
    __shared__ __align__(16) float xs[4 * WSLICE];   // 52224 B

    const int tid  = threadIdx.x;
    const int wv   = tid >> 6;
    const int lane = tid & 63;
    const int pg   = blockIdx.x * 4 + wv;            // this wave's pair-group
    const int quad = lane >> 4, mrow = lane & 15;
    float* wx = xs + wv * WSLICE;

    // ---- stage 16 rows x 200 floats (coalesced float4 -> wave-private LDS) ----
    {
        const float4* xg = (const float4*)(x + (size_t)pg * 16 * TT);
        #pragma unroll
        for (int it = 0; it < 13; it++) {
            int idx = lane + it * 64;
            if (idx < 800) {
                float4 v = xg[idx];
                int p = idx / 50, t4 = (idx % 50) * 4;
                *(float4*)(wx + p * XSTR + t4) = v;
            }
        }
    }

    f32x4 acc[3][4];
    #pragma unroll
    for (int a = 0; a < 3; a++)
        #pragma unroll
        for (int b = 0; b < 4; b++) acc[a][b] = f32x4{0.f, 0.f, 0.f, 0.f};

    float m = -3.4e38f;                              // raw-sample max (this lane's share)
    const int4* bg = (const int4*)bfr;
    const float* rbase = wx + mrow * XSTR;           // this lane's pair-row

    // ---- MFMA: ks-outer (8 table frags live), segs inner ----
    #pragma unroll 1
    for (int ks = 0; ks < 4; ks++) {
        bf16x8 Th[4], Tl[4];
        #pragma unroll
        for (int nt = 0; nt < 4; nt++) {
            BFU uh, ul;
            uh.v = bg[((ks * 4 + nt) * 2 + 0) * 64 + lane];
            ul.v = bg[((ks * 4 + nt) * 2 + 1) * 64 + lane];
            Th[nt] = uh.b;
            Tl[nt] = ul.b;
        }
        #pragma unroll
        for (int sg = 0; sg < 3; sg++) {
            float f[8];
            if (ks < 3) {
                const float* s = rbase + sg * 50 + ks * 32 + quad * 8;   // 8B-aligned
                float2 f0 = *(const float2*)(s);
                float2 f1 = *(const float2*)(s + 2);
                float2 f2 = *(const float2*)(s + 4);
                float2 f3 = *(const float2*)(s + 6);
                f[0] = f0.x; f[1] = f0.y; f[2] = f1.x; f[3] = f1.y;
                f[4] = f2.x; f[5] = f2.y; f[6] = f3.x; f[7] = f3.y;
                if (sg != 1) {
                    m = fmaxf(m, fmaxf(fmaxf(f[0], f[1]), fmaxf(f[2], f[3])));
                    m = fmaxf(m, fmaxf(fmaxf(f[4], f[5]), fmaxf(f[6], f[7])));
                }
            } else {
                // k = 96..127: only k=96..99 real (quad==0 slots); rest 0.
                const float* s = rbase + sg * 50 + 96;                   // floats 196..199 max
                float2 f0 = *(const float2*)(s);
                float2 f1 = *(const float2*)(s + 2);
                if (sg != 1)
                    m = fmaxf(m, fmaxf(fmaxf(f0.x, f0.y), fmaxf(f1.x, f1.y)));
                bool v0 = (quad == 0);
                f[0] = v0 ? f0.x : 0.f; f[1] = v0 ? f0.y : 0.f;
                f[2] = v0 ? f1.x : 0.f; f[3] = v0 ? f1.y : 0.f;
                f[4] = 0.f; f[5] = 0.f; f[6] = 0.f; f[7] = 0.f;
            }
            bf16x8 Xh, Xl;
            #pragma unroll
            for (int i = 0; i < 8; i++) {
                __bf16 hb = (__bf16)f[i];
                Xh[i] = hb;
                Xl[i] = (__bf16)(f[i] - (float)hb);
            }
            __builtin_amdgcn_s_setprio(1);
            #pragma unroll
            for (int nt = 0; nt < 4; nt++) {
                acc[sg][nt] = __builtin_amdgcn_mfma_f32_16x16x32_bf16(Th[nt], Xl, acc[sg][nt], 0, 0, 0);
                acc[sg][nt] = __builtin_amdgcn_mfma_f32_16x16x32_bf16(Tl[nt], Xh, acc[sg][nt], 0, 0, 0);
                acc[sg][nt] = __builtin_amdgcn_mfma_f32_16x16x32_bf16(Th[nt], Xh, acc[sg][nt], 0, 0, 0);
            }
            __builtin_amdgcn_s_setprio(0);
        }
    }

    // ---- in-register band reduce ----
    // lane holds D[j = nt*16 + quad*4 + i][pair = mrow]; bands (j, inclusive):
    // d:0..7  t:6..15  a:14..25  b:24..59; j==0 detrended by 25*mu; mu at j==60
    // (nt=3, quad=3, i=0). Masks depend only on (nt,i) compile-time + quad.
    float s0 = 0.f, s1 = 0.f, s2 = 0.f, s3 = 0.f;
    float mu0 = 0.f, mu2 = 0.f;
    #pragma unroll
    for (int sg = 0; sg < 3; sg++) {
        float mu = __shfl(acc[sg][3][0], 48 | mrow, 64);   // D[60][mrow] broadcast
        if (sg == 0) mu0 = mu;
        if (sg == 2) mu2 = mu;
        #pragma unroll
        for (int nt = 0; nt < 4; nt++) {
            #pragma unroll
            for (int i = 0; i < 4; i++) {
                float v = acc[sg][nt][i];
                if (nt == 0 && i == 0) v += (quad == 0) ? 25.f * mu : 0.f;  // detrend j=0
                float w = v * v;
                if (nt == 0) {
                    s0 += (quad <= 1) ? w : 0.f;                 // j 0..7
                    s1 += (quad * 4 + i >= 6) ? w : 0.f;         // j 6..15
                    if (i >= 2) s2 += (quad == 3) ? w : 0.f;     // j 14,15
                } else if (nt == 1) {
                    s2 += (quad * 4 + i <= 9) ? w : 0.f;         // j 16..25
                    s3 += (quad >= 2) ? w : 0.f;                 // j 24..31
                } else if (nt == 2) {
                    s3 += w;                                     // j 32..47
                } else {
                    s3 += (quad <= 2) ? w : 0.f;                 // j 48..59 (excl. 60+)
                }
            }
        }
    }
    // reduce bands + max across the 4 quads of each pair-row
    s0 += __shfl_xor(s0, 16, 64); s1 += __shfl_xor(s1, 16, 64);
    s2 += __shfl_xor(s2, 16, 64); s3 += __shfl_xor(s3, 16, 64);
    s0 += __shfl_xor(s0, 32, 64); s1 += __shfl_xor(s1, 32, 64);
    s2 += __shfl_xor(s2, 32, 64); s3 += __shfl_xor(s3, 32, 64);
    m = fmaxf(m, __shfl_xor(m, 16, 64));
    m = fmaxf(m, __shfl_xor(m, 32, 64));

    if (quad == 0) {
        int pr = pg * 16 + mrow;
        float4 fo;
        fo.x = s0 * (2.f / 45000.f);
        fo.y = s1 * (2.f / 56250.f);
        fo.z = s2 * (2.f / 67500.f);
        fo.w = s3 * (2.f / 202500.f);
        *(float4*)(feat + (size_t)pr * 4) = fo;
        avg[pr] = (mu0 + mu2) * 0.5f;
        mxg[pr] = m;
    }
}

// ---------------------------------------------------------------------------
// Kernel B: attention + MLP head (reverted to the simple single-buffer form).
// ---------------------------------------------------------------------------
__global__ __launch_bounds__(256, 8) void kB(const float* __restrict__ avg,
                                             const float* __restrict__ mxv,
                                             const float* __restrict__ feat,
                                             const float* __restrict__ w_att1,
                                             const float* __restrict__ w_att2,
                                             const float* __restrict__ w_bb,
                                             const float* __restrict__ b_bb,
                                             const float* __restrict__ w_fe1,
                                             const float* __restrict__ b_fe1,
                                             const float* __restrict__ w_fe2,
                                             const float* __restrict__ b_fe2,
                                             const float* __restrict__ w_h1,
                                             const float* __restrict__ b_h1,
                                             const float* __restrict__ w_h2,
                                             const float* __restrict__ b_h2,
                                             const float* __restrict__ w_h3,
                                             const float* __restrict__ b_h3,
                                             float* __restrict__ out) {
    __shared__ float s_avg[132], s_mx[132], s_fq[520];
    __shared__ float s_t1a[16], s_t1b[16], s_t1[16];
    __shared__ float s_v[132];
    __shared__ float s_tf[2][64];
    __shared__ float s_p1[2][128];
    __shared__ float s_f1[128];
    __shared__ float s_p2[4][64];
    __shared__ float s_h[128];
    __shared__ float s_pg1[2][128];
    __shared__ float s_g1[128];
    __shared__ float s_pg2[4][64];

    const int b = blockIdx.x;
    const int tid = threadIdx.x;

    for (int i = tid; i < 129; i += 256) { s_avg[i] = avg[b * 129 + i]; s_mx[i] = mxv[b * 129 + i]; }
    for (int i = tid; i < 516; i += 256) s_fq[i] = feat[(size_t)b * 516 + i];
    __syncthreads();

    if (tid < 32) {
        int h = tid & 15;
        const float* src = (tid >= 16) ? s_mx : s_avg;
        float acc = 0.f;
        #pragma unroll 4
        for (int c = 0; c < 129; c++) acc += src[c] * w_att1[c * 16 + h];
        ((tid >= 16) ? s_t1b : s_t1a)[h] = fmaxf(acc, 0.f);
    }
    __syncthreads();
    if (tid < 16) s_t1[tid] = s_t1a[tid] + s_t1b[tid];
    __syncthreads();

    if (tid < 129) {
        float l = 0.f;
        #pragma unroll
        for (int j = 0; j < 16; j++) l += s_t1[j] * w_att2[j * 129 + tid];
        s_v[tid] = s_avg[tid] / (1.f + expf(-l));
    }
    __syncthreads();

    if (tid < 128) {
        int o = tid & 63, ks = tid >> 6;
        int i0 = ks ? 65 : 0, i1 = ks ? 129 : 65;
        float acc = 0.f;
        #pragma unroll 4
        for (int i = i0; i < i1; i++) acc += s_v[i] * w_bb[i * 64 + o];
        s_tf[ks][o] = acc;
    }
    {
        int o = tid & 127, ks = tid >> 7;
        float acc = 0.f;
        #pragma unroll 4
        for (int i = ks * 258; i < ks * 258 + 258; i++) acc += s_fq[i] * w_fe1[i * 128 + o];
        s_p1[ks][o] = acc;
    }
    __syncthreads();
    if (tid < 64) s_h[tid] = fmaxf(s_tf[0][tid] + s_tf[1][tid] + b_bb[tid], 0.f);
    if (tid >= 128) { int o = tid - 128; s_f1[o] = fmaxf(s_p1[0][o] + s_p1[1][o] + b_fe1[o], 0.f); }
    __syncthreads();

    {
        int o = tid & 63, ks = tid >> 6;
        float acc = 0.f;
        #pragma unroll 4
        for (int i = ks * 32; i < ks * 32 + 32; i++) acc += s_f1[i] * w_fe2[i * 64 + o];
        s_p2[ks][o] = acc;
    }
    __syncthreads();
    if (tid < 64) s_h[64 + tid] = fmaxf(s_p2[0][tid] + s_p2[1][tid] + s_p2[2][tid] + s_p2[3][tid] + b_fe2[tid], 0.f);
    __syncthreads();

    {
        int o = tid & 127, ks = tid >> 7;
        float acc = 0.f;
        #pragma unroll 4
        for (int i = ks * 64; i < ks * 64 + 64; i++) acc += s_h[i] * w_h1[i * 128 + o];
        s_pg1[ks][o] = acc;
    }
    __syncthreads();
    if (tid < 128) s_g1[tid] = fmaxf(s_pg1[0][tid] + s_pg1[1][tid] + b_h1[tid], 0.f);
    __syncthreads();

    {
        int o = tid & 63, ks = tid >> 6;
        float acc = 0.f;
        #pragma unroll 4
        for (int i = ks * 32; i < ks * 32 + 32; i++) acc += s_g1[i] * w_h2[i * 64 + o];
        s_pg2[ks][o] = acc;
    }
    __syncthreads();

    if (tid < 64) {
        float g2 = fmaxf(s_pg2[0][tid] + s_pg2[1][tid] + s_pg2[2][tid] + s_pg2[3][tid] + b_h2[tid], 0.f);
        float pz = g2 * w_h3[tid];
        for (int off = 32; off >= 1; off >>= 1) pz += __shfl_xor(pz, off, 64);
        if (tid == 0) out[b] = pz + b_h3[0];
    }
}

// ---------------------------------------------------------------------------
extern "C" void kernel_launch(void* const* d_in, const int* in_sizes, int n_in,
                              void* d_out, int out_size, void* d_ws, size_t ws_size,
                              hipStream_t stream) {
    const float* x      = (const float*)d_in[0];
    const float* w_att1 = (const float*)d_in[1];
    const float* w_att2 = (const float*)d_in[2];
    const float* w_bb   = (const float*)d_in[3];
    const float* b_bb   = (const float*)d_in[4];
    const float* w_fe1  = (const float*)d_in[5];
    const float* b_fe1  = (const float*)d_in[6];
    const float* w_fe2  = (const float*)d_in[7];
    const float* b_fe2  = (const float*)d_in[8];
    const float* w_h1   = (const float*)d_in[9];
    const float* b_h1   = (const float*)d_in[10];
    const float* w_h2   = (const float*)d_in[11];
    const float* b_h2   = (const float*)d_in[12];
    const float* w_h3   = (const float*)d_in[13];
    const float* b_h3   = (const float*)d_in[14];

    float* ws = (float*)d_ws;
    unsigned short* bfr = (unsigned short*)ws;     // 16384 bf16 = 8192 floats
    float* avg  = ws + OFF_AVG;
    float* mxv  = ws + OFF_MX;
    float* feat = ws + OFF_FT;

    kInit<<<64, 256, 0, stream>>>(bfr);
    kA<<<NBLK, 256, 0, stream>>>(x, bfr, avg, mxv, feat);
    kB<<<BB, 256, 0, stream>>>(avg, mxv, feat,
                               w_att1, w_att2, w_bb, b_bb,
                               w_fe1, b_fe1, w_fe2, b_fe2,
                               w_h1, b_h1, w_h2, b_h2, w_h3, b_h3,
                               (float*)d_out);
}

// Round 5
// 415.834 us; speedup vs baseline: 1.1124x; 1.0079x over previous
//
#include <hip/hip_runtime.h>
#include <math.h>

// Problem constants
constexpr int BB = 2048;     // batch
constexpr int CC = 129;      // channels
constexpr int TT = 200;      // time
constexpr int NPAIR = BB * CC;          // 264192
constexpr int NPG   = NPAIR / 16;       // 16512 pair-groups (16 pairs each)
constexpr int NBLK  = NPG / 4;          // 4128 blocks (4 waves, 1 pg per wave)
constexpr int WSL   = 3200;             // floats per wave slice (16 rows x 200)

// d_ws layout (in floats)
constexpr int OFF_AVG = 8192;           // B-frags occupy 16384 bf16 = 8192 floats
constexpr int OFF_MX  = OFF_AVG + NPAIR;
constexpr int OFF_FT  = OFF_MX + NPAIR; // NPAIR*4 floats

typedef __bf16 bf16x8 __attribute__((ext_vector_type(8)));
typedef float  f32x4  __attribute__((ext_vector_type(4)));

union BFU { int4 v; bf16x8 b; };
union BSU { __bf16 b; unsigned short u; };

typedef __attribute__((address_space(3))) char  lds_char;
typedef const __attribute__((address_space(1))) void g_void;

// ---------------------------------------------------------------------------
// kInit: build W (128 k-rows x 64 n-cols) as MFMA fragments, split bf16
// hi/lo, pre-swizzled in fragment order:
//   bfr[((ks*4+nt)*2+h)*512 + lane*8 + i]  (ushort)
// Element (ks,nt,h,lane,i) = W[k = ks*32 + (lane>>4)*8 + i][n = nt*16 + (lane&15)]
//   n<60: bin kb=(n>>1)+1, even n -> w[t]*cos, odd n -> w[t]*sin
//   n==60: 1/100 (k<100)  -> GEMM emits segment mean (detrend + avg for free)
//   k>=100 or n>60: 0 (K padding / unused cols)
// ---------------------------------------------------------------------------
__global__ void kInit(unsigned short* __restrict__ bfr) {
    int tid = blockIdx.x * 256 + threadIdx.x;
    if (tid >= 16384) return;
    int i    = tid & 7;
    int lane = (tid >> 3) & 63;
    int h    = (tid >> 9) & 1;
    int nt   = (tid >> 10) & 3;
    int ks   = tid >> 12;
    int k = ks * 32 + (lane >> 4) * 8 + i;
    int n = nt * 16 + (lane & 15);
    float v = 0.f;
    if (k < 100) {
        if (n < 60) {
            int kb = (n >> 1) + 1;
            const float C = 0.06283185307179587f;      // 2*pi/100
            float w = 0.5f - 0.5f * cosf(C * (float)k);
            int ph = (kb * k) % 100;                   // exact phase reduction
            float ang = C * (float)ph;
            v = w * ((n & 1) ? sinf(ang) : cosf(ang));
        } else if (n == 60) {
            v = 0.01f;
        }
    }
    __bf16 hb = (__bf16)v;
    BSU out;
    if (h == 0) out.b = hb;
    else        out.b = (__bf16)(v - (float)hb);
    bfr[tid] = out.u;
}

// ---------------------------------------------------------------------------
// Kernel A v6: async global_load_lds staging into a COLUMN-MAJOR-f4 LDS
// image; transposed GEMM + in-register band reduce (v5) otherwise unchanged.
//
// LDS layout: f4-slot s = c4*16 + r  (c4 = float4-column 0..49, r = row 0..15)
//   -> float offset 64*c4 + 4*r.  Realized for free: global_load_lds writes
//   linearly (dest slot = it*64 + lane), so the PER-LANE GLOBAL address is
//   permuted instead: c4 = it*4 + (lane>>4), r = lane&15 (rule: swizzle
//   source + read, never the dest).
//  - staging: 13 descriptor-free global_load_lds (no VGPRs -> compiler
//    cannot serialize it), ONE vmcnt(0) fence. ks=0 table load hoisted
//    before the fence (latency merges with stage wait).
//  - frag read: 2x ds_read_b128 at base+imm (256B contiguous across the
//    16 rows) -> bank-throughput floor, ZERO excess conflicts (v5 was
//    8-way). Odd segments (offset 50 floats = 12.5 slots) reassemble
//    f[0..7] from b128+b128+b64 by static register naming (0 extra VALU).
//  - zero barriers, wave-autonomous, 3 blocks/CU.
// spec = Wh*Xh + Wl*Xh + Wh*Xl  (~2^-18 rel err, unchanged).
// ---------------------------------------------------------------------------
__global__ __launch_bounds__(256, 3) void kA(const float* __restrict__ x,
                                             const unsigned short* __restrict__ bfr,
                                             float* __restrict__ avg,
                                             float* __restrict__ mxg,
                                             float* __restrict__ feat) {
    __shared__ __align__(16) float xs[4 * WSL];      // 51200 B

    const int tid  = threadIdx.x;
    const int wv   = tid >> 6;
    const int lane = tid & 63;
    const int pg   = blockIdx.x * 4 + wv;            // this wave's pair-group
    const int quad = lane >> 4, mrow = lane & 15;
    float* wx = xs + wv * WSL;

    // ---- stage: 13 async global_load_lds, col-major-f4 image ----
    {
        // lane supplies global float4 (row = lane&15, c4 = it*4 + (lane>>4))
        const float* gp = x + (size_t)pg * 16 * TT + (lane & 15) * TT + (lane >> 4) * 4;
        lds_char* lp = (lds_char*)wx;
        #pragma unroll
        for (int it = 0; it < 12; it++) {
            __builtin_amdgcn_global_load_lds((g_void*)(gp + it * 16),
                                             (__attribute__((address_space(3))) void*)(lp + it * 1024),
                                             16, 0, 0);
        }
        if (lane < 32) {   // slots 768..799 (c4 48..49, all rows)
            __builtin_amdgcn_global_load_lds((g_void*)(gp + 12 * 16),
                                             (__attribute__((address_space(3))) void*)(lp + 12 * 1024),
                                             16, 0, 0);
        }
    }

    // ---- table ks=0 prefetch (latency merges with stage wait) ----
    const int4* bg = (const int4*)bfr;
    bf16x8 Th[4], Tl[4];
    #pragma unroll
    for (int nt = 0; nt < 4; nt++) {
        BFU uh, ul;
        uh.v = bg[(nt * 2 + 0) * 64 + lane];
        ul.v = bg[(nt * 2 + 1) * 64 + lane];
        Th[nt] = uh.b;
        Tl[nt] = ul.b;
    }

    f32x4 acc[3][4];
    #pragma unroll
    for (int a = 0; a < 3; a++)
        #pragma unroll
        for (int b = 0; b < 4; b++) acc[a][b] = f32x4{0.f, 0.f, 0.f, 0.f};

    // single drain: stage + ks0 table complete
    asm volatile("s_waitcnt vmcnt(0)" ::: "memory");
    __builtin_amdgcn_sched_barrier(0);

    float m = -3.4e38f;                              // raw-sample max (lane's share)
    const float* lbq = wx + mrow * 4 + quad * 128;   // + 64*s0(base) compile-time
    const float* lb0 = wx + mrow * 4;                // quad-independent reads (ks=3)

    #pragma unroll 1
    for (int ks = 0; ks < 4; ks++) {
        if (ks > 0) {
            #pragma unroll
            for (int nt = 0; nt < 4; nt++) {
                BFU uh, ul;
                uh.v = bg[((ks * 4 + nt) * 2 + 0) * 64 + lane];
                ul.v = bg[((ks * 4 + nt) * 2 + 1) * 64 + lane];
                Th[nt] = uh.b;
                Tl[nt] = ul.b;
            }
        }
        #pragma unroll
        for (int sg = 0; sg < 3; sg++) {
            float f[8];
            if (ks < 3) {
                if (sg != 1) {
                    // aligned: slots s0 = (sg?25:0)+8ks+2q, s0+1
                    const float* s = ((sg == 0) ? lbq : (lbq + 25 * 64)) + ks * 512;
                    float4 A  = *(const float4*)(s);
                    float4 Bv = *(const float4*)(s + 64);
                    f[0] = A.x;  f[1] = A.y;  f[2] = A.z;  f[3] = A.w;
                    f[4] = Bv.x; f[5] = Bv.y; f[6] = Bv.z; f[7] = Bv.w;
                    m = fmaxf(m, fmaxf(fmaxf(f[0], f[1]), fmaxf(f[2], f[3])));
                    m = fmaxf(m, fmaxf(fmaxf(f[4], f[5]), fmaxf(f[6], f[7])));
                } else {
                    // odd seg: floats F=50+32ks+8q -> slots s0=12+8ks+2q (x2), +b64
                    const float* s = lbq + 12 * 64 + ks * 512;
                    float4 A  = *(const float4*)(s);
                    float4 Bv = *(const float4*)(s + 64);
                    float2 Cv = *(const float2*)(s + 128);
                    f[0] = A.z;  f[1] = A.w;  f[2] = Bv.x; f[3] = Bv.y;
                    f[4] = Bv.z; f[5] = Bv.w; f[6] = Cv.x; f[7] = Cv.y;
                }
            } else {
                // k = 96..99 only (quad==0 slots); rest 0.
                bool v0 = (quad == 0);
                if (sg != 1) {
                    const float* s = lb0 + ((sg == 0) ? 24 : 49) * 64;  // floats 96..99 / 196..199
                    float4 A = *(const float4*)(s);
                    m = fmaxf(m, fmaxf(fmaxf(A.x, A.y), fmaxf(A.z, A.w)));
                    f[0] = v0 ? A.x : 0.f; f[1] = v0 ? A.y : 0.f;
                    f[2] = v0 ? A.z : 0.f; f[3] = v0 ? A.w : 0.f;
                } else {
                    const float* s = lb0 + 36 * 64;                     // floats 144..147 / 148..149
                    float4 A  = *(const float4*)(s);
                    float2 Cv = *(const float2*)(s + 64);
                    f[0] = v0 ? A.z : 0.f;  f[1] = v0 ? A.w : 0.f;
                    f[2] = v0 ? Cv.x : 0.f; f[3] = v0 ? Cv.y : 0.f;
                }
                f[4] = 0.f; f[5] = 0.f; f[6] = 0.f; f[7] = 0.f;
            }
            bf16x8 Xh, Xl;
            #pragma unroll
            for (int i = 0; i < 8; i++) {
                __bf16 hb = (__bf16)f[i];
                Xh[i] = hb;
                Xl[i] = (__bf16)(f[i] - (float)hb);
            }
            __builtin_amdgcn_s_setprio(1);
            #pragma unroll
            for (int nt = 0; nt < 4; nt++) {
                acc[sg][nt] = __builtin_amdgcn_mfma_f32_16x16x32_bf16(Th[nt], Xl, acc[sg][nt], 0, 0, 0);
                acc[sg][nt] = __builtin_amdgcn_mfma_f32_16x16x32_bf16(Tl[nt], Xh, acc[sg][nt], 0, 0, 0);
                acc[sg][nt] = __builtin_amdgcn_mfma_f32_16x16x32_bf16(Th[nt], Xh, acc[sg][nt], 0, 0, 0);
            }
            __builtin_amdgcn_s_setprio(0);
        }
    }

    // ---- in-register band reduce ----
    // lane holds D[j = nt*16 + quad*4 + i][pair = mrow]; bands (j, inclusive):
    // d:0..7  t:6..15  a:14..25  b:24..59; j==0 detrended by 25*mu; mu at j==60
    // (nt=3, quad=3, i=0). Masks depend only on (nt,i) compile-time + quad.
    float s0 = 0.f, s1 = 0.f, s2 = 0.f, s3 = 0.f;
    float mu0 = 0.f, mu2 = 0.f;
    #pragma unroll
    for (int sg = 0; sg < 3; sg++) {
        float mu = __shfl(acc[sg][3][0], 48 | mrow, 64);   // D[60][mrow] broadcast
        if (sg == 0) mu0 = mu;
        if (sg == 2) mu2 = mu;
        #pragma unroll
        for (int nt = 0; nt < 4; nt++) {
            #pragma unroll
            for (int i = 0; i < 4; i++) {
                float v = acc[sg][nt][i];
                if (nt == 0 && i == 0) v += (quad == 0) ? 25.f * mu : 0.f;  // detrend j=0
                float w = v * v;
                if (nt == 0) {
                    s0 += (quad <= 1) ? w : 0.f;                 // j 0..7
                    s1 += (quad * 4 + i >= 6) ? w : 0.f;         // j 6..15
                    if (i >= 2) s2 += (quad == 3) ? w : 0.f;     // j 14,15
                } else if (nt == 1) {
                    s2 += (quad * 4 + i <= 9) ? w : 0.f;         // j 16..25
                    s3 += (quad >= 2) ? w : 0.f;                 // j 24..31
                } else if (nt == 2) {
                    s3 += w;                                     // j 32..47
                } else {
                    s3 += (quad <= 2) ? w : 0.f;                 // j 48..59 (excl. 60+)
                }
            }
        }
    }
    // reduce bands + max across the 4 quads of each pair-row
    s0 += __shfl_xor(s0, 16, 64); s1 += __shfl_xor(s1, 16, 64);
    s2 += __shfl_xor(s2, 16, 64); s3 += __shfl_xor(s3, 16, 64);
    s0 += __shfl_xor(s0, 32, 64); s1 += __shfl_xor(s1, 32, 64);
    s2 += __shfl_xor(s2, 32, 64); s3 += __shfl_xor(s3, 32, 64);
    m = fmaxf(m, __shfl_xor(m, 16, 64));
    m = fmaxf(m, __shfl_xor(m, 32, 64));

    if (quad == 0) {
        int pr = pg * 16 + mrow;
        float4 fo;
        fo.x = s0 * (2.f / 45000.f);
        fo.y = s1 * (2.f / 56250.f);
        fo.z = s2 * (2.f / 67500.f);
        fo.w = s3 * (2.f / 202500.f);
        *(float4*)(feat + (size_t)pr * 4) = fo;
        avg[pr] = (mu0 + mu2) * 0.5f;
        mxg[pr] = m;
    }
}

// ---------------------------------------------------------------------------
// Kernel B: attention + MLP head (unchanged simple form).
// ---------------------------------------------------------------------------
__global__ __launch_bounds__(256, 8) void kB(const float* __restrict__ avg,
                                             const float* __restrict__ mxv,
                                             const float* __restrict__ feat,
                                             const float* __restrict__ w_att1,
                                             const float* __restrict__ w_att2,
                                             const float* __restrict__ w_bb,
                                             const float* __restrict__ b_bb,
                                             const float* __restrict__ w_fe1,
                                             const float* __restrict__ b_fe1,
                                             const float* __restrict__ w_fe2,
                                             const float* __restrict__ b_fe2,
                                             const float* __restrict__ w_h1,
                                             const float* __restrict__ b_h1,
                                             const float* __restrict__ w_h2,
                                             const float* __restrict__ b_h2,
                                             const float* __restrict__ w_h3,
                                             const float* __restrict__ b_h3,
                                             float* __restrict__ out) {
    __shared__ float s_avg[132], s_mx[132], s_fq[520];
    __shared__ float s_t1a[16], s_t1b[16], s_t1[16];
    __shared__ float s_v[132];
    __shared__ float s_tf[2][64];
    __shared__ float s_p1[2][128];
    __shared__ float s_f1[128];
    __shared__ float s_p2[4][64];
    __shared__ float s_h[128];
    __shared__ float s_pg1[2][128];
    __shared__ float s_g1[128];
    __shared__ float s_pg2[4][64];

    const int b = blockIdx.x;
    const int tid = threadIdx.x;

    for (int i = tid; i < 129; i += 256) { s_avg[i] = avg[b * 129 + i]; s_mx[i] = mxv[b * 129 + i]; }
    for (int i = tid; i < 516; i += 256) s_fq[i] = feat[(size_t)b * 516 + i];
    __syncthreads();

    if (tid < 32) {
        int h = tid & 15;
        const float* src = (tid >= 16) ? s_mx : s_avg;
        float acc = 0.f;
        #pragma unroll 4
        for (int c = 0; c < 129; c++) acc += src[c] * w_att1[c * 16 + h];
        ((tid >= 16) ? s_t1b : s_t1a)[h] = fmaxf(acc, 0.f);
    }
    __syncthreads();
    if (tid < 16) s_t1[tid] = s_t1a[tid] + s_t1b[tid];
    __syncthreads();

    if (tid < 129) {
        float l = 0.f;
        #pragma unroll
        for (int j = 0; j < 16; j++) l += s_t1[j] * w_att2[j * 129 + tid];
        s_v[tid] = s_avg[tid] / (1.f + expf(-l));
    }
    __syncthreads();

    if (tid < 128) {
        int o = tid & 63, ks = tid >> 6;
        int i0 = ks ? 65 : 0, i1 = ks ? 129 : 65;
        float acc = 0.f;
        #pragma unroll 4
        for (int i = i0; i < i1; i++) acc += s_v[i] * w_bb[i * 64 + o];
        s_tf[ks][o] = acc;
    }
    {
        int o = tid & 127, ks = tid >> 7;
        float acc = 0.f;
        #pragma unroll 4
        for (int i = ks * 258; i < ks * 258 + 258; i++) acc += s_fq[i] * w_fe1[i * 128 + o];
        s_p1[ks][o] = acc;
    }
    __syncthreads();
    if (tid < 64) s_h[tid] = fmaxf(s_tf[0][tid] + s_tf[1][tid] + b_bb[tid], 0.f);
    if (tid >= 128) { int o = tid - 128; s_f1[o] = fmaxf(s_p1[0][o] + s_p1[1][o] + b_fe1[o], 0.f); }
    __syncthreads();

    {
        int o = tid & 63, ks = tid >> 6;
        float acc = 0.f;
        #pragma unroll 4
        for (int i = ks * 32; i < ks * 32 + 32; i++) acc += s_f1[i] * w_fe2[i * 64 + o];
        s_p2[ks][o] = acc;
    }
    __syncthreads();
    if (tid < 64) s_h[64 + tid] = fmaxf(s_p2[0][tid] + s_p2[1][tid] + s_p2[2][tid] + s_p2[3][tid] + b_fe2[tid], 0.f);
    __syncthreads();

    {
        int o = tid & 127, ks = tid >> 7;
        float acc = 0.f;
        #pragma unroll 4
        for (int i = ks * 64; i < ks * 64 + 64; i++) acc += s_h[i] * w_h1[i * 128 + o];
        s_pg1[ks][o] = acc;
    }
    __syncthreads();
    if (tid < 128) s_g1[tid] = fmaxf(s_pg1[0][tid] + s_pg1[1][tid] + b_h1[tid], 0.f);
    __syncthreads();

    {
        int o = tid & 63, ks = tid >> 6;
        float acc = 0.f;
        #pragma unroll 4
        for (int i = ks * 32; i < ks * 32 + 32; i++) acc += s_g1[i] * w_h2[i * 64 + o];
        s_pg2[ks][o] = acc;
    }
    __syncthreads();

    if (tid < 64) {
        float g2 = fmaxf(s_pg2[0][tid] + s_pg2[1][tid] + s_pg2[2][tid] + s_pg2[3][tid] + b_h2[tid], 0.f);
        float pz = g2 * w_h3[tid];
        for (int off = 32; off >= 1; off >>= 1) pz += __shfl_xor(pz, off, 64);
        if (tid == 0) out[b] = pz + b_h3[0];
    }
}

// ---------------------------------------------------------------------------
extern "C" void kernel_launch(void* const* d_in, const int* in_sizes, int n_in,
                              void* d_out, int out_size, void* d_ws, size_t ws_size,
                              hipStream_t stream) {
    const float* x      = (const float*)d_in[0];
    const float* w_att1 = (const float*)d_in[1];
    const float* w_att2 = (const float*)d_in[2];
    const float* w_bb   = (const float*)d_in[3];
    const float* b_bb   = (const float*)d_in[4];
    const float* w_fe1  = (const float*)d_in[5];
    const float* b_fe1  = (const float*)d_in[6];
    const float* w_fe2  = (const float*)d_in[7];
    const float* b_fe2  = (const float*)d_in[8];
    const float* w_h1   = (const float*)d_in[9];
    const float* b_h1   = (const float*)d_in[10];
    const float* w_h2   = (const float*)d_in[11];
    const float* b_h2   = (const float*)d_in[12];
    const float* w_h3   = (const float*)d_in[13];
    const float* b_h3   = (const float*)d_in[14];

    float* ws = (float*)d_ws;
    unsigned short* bfr = (unsigned short*)ws;     // 16384 bf16 = 8192 floats
    float* avg  = ws + OFF_AVG;
    float* mxv  = ws + OFF_MX;
    float* feat = ws + OFF_FT;

    kInit<<<64, 256, 0, stream>>>(bfr);
    kA<<<NBLK, 256, 0, stream>>>(x, bfr, avg, mxv, feat);
    kB<<<BB, 256, 0, stream>>>(avg, mxv, feat,
                               w_att1, w_att2, w_bb, b_bb,
                               w_fe1, b_fe1, w_fe2, b_fe2,
                               w_h1, b_h1, w_h2, b_h2, w_h3, b_h3,
                               (float*)d_out);
}